// Round 9
// baseline (966.565 us; speedup 1.0000x reference)
//
#include <hip/hip_runtime.h>
#include <cstdint>
#include <cstddef>

#define H 4
#define DK 128
#define DV 256
#define NH 2
#define HID 1024
#define KSZ 4
#define NTOT 4608  // packed projection width: 512 q | 1024 k | 2048 v | 1024 g

#define CH 16            // chunk length
#define UPD 32           // updates per chunk = CH*NH
#define NCHK 64          // 1024 / CH
#define EREC 576         // E-record stride (floats): 512 E + 16 Gq + 32 f + 1 GC + pad

typedef __bf16 bfx8 __attribute__((ext_vector_type(8)));
typedef float f32x4 __attribute__((ext_vector_type(4)));

__device__ __forceinline__ float wave_sum(float x) {
#pragma unroll
  for (int off = 1; off < 64; off <<= 1) x += __shfl_xor(x, off, 64);
  return x;
}

__device__ __forceinline__ ushort f2bf(float x) {
  uint u = __float_as_uint(x);
  return (ushort)((u + 0x7fffu + ((u >> 16) & 1u)) >> 16);
}

#define DPP_ADD(x, ctrl) \
  x += __int_as_float(__builtin_amdgcn_update_dpp(0, __float_as_int(x), ctrl, 0xf, 0xf, true))

// N independent full-wave64 sums, interleaved DPP chains; results uniform via readlane(63)
template <int N>
__device__ __forceinline__ void dpp_reduce(float (&d)[N]) {
#pragma unroll
  for (int i = 0; i < N; i++) DPP_ADD(d[i], 0x111);
#pragma unroll
  for (int i = 0; i < N; i++) DPP_ADD(d[i], 0x112);
#pragma unroll
  for (int i = 0; i < N; i++) DPP_ADD(d[i], 0x114);
#pragma unroll
  for (int i = 0; i < N; i++) DPP_ADD(d[i], 0x118);
#pragma unroll
  for (int i = 0; i < N; i++) DPP_ADD(d[i], 0x142);
#pragma unroll
  for (int i = 0; i < N; i++) DPP_ADD(d[i], 0x143);
#pragma unroll
  for (int i = 0; i < N; i++)
    d[i] = __int_as_float(__builtin_amdgcn_readlane(__float_as_int(d[i]), 63));
}

// ---------------- fp32 -> bf16 cast, 4 elems/thread
__global__ __launch_bounds__(256) void cast_hs(const float* __restrict__ src,
                                               ushort* __restrict__ dst) {
  int i = blockIdx.x * 256 + threadIdx.x;
  float4 v = ((const float4*)src)[i];
  ushort4 o = {f2bf(v.x), f2bf(v.y), f2bf(v.z), f2bf(v.w)};
  ((ushort4*)dst)[i] = o;
}

// ---------------- transpose+cast packed weights: Bt[4608][1024] bf16
__global__ __launch_bounds__(256) void tr_pack(const float* __restrict__ Wq,
                                               const float* __restrict__ Wk,
                                               const float* __restrict__ Wv,
                                               const float* __restrict__ Wg,
                                               ushort* __restrict__ Bt) {
  __shared__ float tile[32][33];
  int n0 = blockIdx.x * 32, k0 = blockIdx.y * 32;
  const float* src;
  int ld, nb;
  if (n0 < 512)       { src = Wq; ld = 512;  nb = n0; }
  else if (n0 < 1536) { src = Wk; ld = 1024; nb = n0 - 512; }
  else if (n0 < 3584) { src = Wv; ld = 2048; nb = n0 - 1536; }
  else                { src = Wg; ld = 1024; nb = n0 - 3584; }
  int tx = threadIdx.x & 31, ty = threadIdx.x >> 5;
#pragma unroll
  for (int i = 0; i < 4; i++)
    tile[ty + i * 8][tx] = src[(size_t)(k0 + ty + i * 8) * ld + nb + tx];
  __syncthreads();
#pragma unroll
  for (int i = 0; i < 4; i++)
    Bt[(size_t)(n0 + ty + i * 8) * 1024 + k0 + tx] = f2bf(tile[tx][ty + i * 8]);
}

// ---------------- transpose+cast single square matrix (Wo)
__global__ __launch_bounds__(256) void tr_one(const float* __restrict__ W,
                                              ushort* __restrict__ Bt, int N) {
  __shared__ float tile[32][33];
  int n0 = blockIdx.x * 32, k0 = blockIdx.y * 32;
  int tx = threadIdx.x & 31, ty = threadIdx.x >> 5;
#pragma unroll
  for (int i = 0; i < 4; i++)
    tile[ty + i * 8][tx] = W[(size_t)(k0 + ty + i * 8) * N + n0 + tx];
  __syncthreads();
#pragma unroll
  for (int i = 0; i < 4; i++)
    Bt[(size_t)(n0 + ty + i * 8) * 1024 + k0 + tx] = f2bf(tile[tx][ty + i * 8]);
}

// ---------------- bf16 MFMA GEMM: C[M,N](fp32, ldc) = A[M,K]bf16 @ Bt[N,K]bf16^T
#define LDP 40
__global__ __launch_bounds__(256) void gemm_bf16(const ushort* __restrict__ A,
                                                 const ushort* __restrict__ Bt,
                                                 float* __restrict__ C,
                                                 int K, int ldc) {
  __shared__ __align__(16) ushort As[128][LDP];
  __shared__ __align__(16) ushort Bs[128][LDP];
  const int tid = threadIdx.x;
  const int lane = tid & 63, wave = tid >> 6;
  const int wr = wave >> 1, wc = wave & 1;
  const int row0 = blockIdx.y * 128, col0 = blockIdx.x * 128;
  const int r = tid >> 1, hf = tid & 1;

  f32x4 acc[4][4];
#pragma unroll
  for (int i = 0; i < 4; i++)
#pragma unroll
    for (int j = 0; j < 4; j++) acc[i][j] = {0.f, 0.f, 0.f, 0.f};

  const int lrow = lane & 15, lk = (lane >> 4) * 8;

  for (int k0 = 0; k0 < K; k0 += 32) {
    const float4* pa = (const float4*)(A + (size_t)(row0 + r) * K + k0 + hf * 16);
    const float4* pb = (const float4*)(Bt + (size_t)(col0 + r) * K + k0 + hf * 16);
    float4 a0 = pa[0], a1 = pa[1];
    float4 b0 = pb[0], b1 = pb[1];
    __syncthreads();
    *(float4*)&As[r][hf * 16] = a0;
    *(float4*)&As[r][hf * 16 + 8] = a1;
    *(float4*)&Bs[r][hf * 16] = b0;
    *(float4*)&Bs[r][hf * 16 + 8] = b1;
    __syncthreads();
    bfx8 af[4], bf[4];
#pragma unroll
    for (int mf = 0; mf < 4; mf++)
      af[mf] = *(const bfx8*)&As[wr * 64 + mf * 16 + lrow][lk];
#pragma unroll
    for (int nf = 0; nf < 4; nf++)
      bf[nf] = *(const bfx8*)&Bs[wc * 64 + nf * 16 + lrow][lk];
#pragma unroll
    for (int mf = 0; mf < 4; mf++)
#pragma unroll
      for (int nf = 0; nf < 4; nf++)
        acc[mf][nf] = __builtin_amdgcn_mfma_f32_16x16x32_bf16(af[mf], bf[nf], acc[mf][nf], 0, 0, 0);
  }
  const int crow = (lane >> 4) * 4, ccol = lane & 15;
#pragma unroll
  for (int mf = 0; mf < 4; mf++)
#pragma unroll
    for (int nf = 0; nf < 4; nf++)
#pragma unroll
      for (int rr = 0; rr < 4; rr++)
        C[(size_t)(row0 + wr * 64 + mf * 16 + crow + rr) * ldc + col0 + wc * 64 + nf * 16 + ccol] =
            acc[mf][nf][rr];
}

// ---------------- beta / g tiny projections (raw g again)
__global__ __launch_bounds__(256) void proj_bg(const float* __restrict__ hs,
                                               const float* __restrict__ Wb,
                                               const float* __restrict__ Wa,
                                               const float* __restrict__ A_log,
                                               const float* __restrict__ dt_bias,
                                               float* __restrict__ beta,
                                               float* __restrict__ g) {
  int row = blockIdx.x;
  int lane = threadIdx.x & 63;
  int wave = threadIdx.x >> 6;
  const float* x = hs + (size_t)row * HID;
  for (int out = wave; out < 12; out += 4) {
    float sum = 0.f;
    if (out < 8) {
      for (int k = lane; k < HID; k += 64) sum = fmaf(x[k], Wb[(size_t)k * 8 + out], sum);
    } else {
      int c = out - 8;
      for (int k = lane; k < HID; k += 64) sum = fmaf(x[k], Wa[(size_t)k * 4 + c], sum);
    }
    sum = wave_sum(sum);
    if (lane == 0) {
      if (out < 8) {
        beta[(size_t)row * 8 + out] = 2.f / (1.f + expf(-sum));
      } else {
        int h = out - 8;
        float xx = sum + dt_bias[h];
        float sp = (xx > 20.f) ? xx : log1pf(expf(xx));
        g[(size_t)row * 4 + h] = -expf(A_log[h]) * sp;
      }
    }
  }
}

// ---------------- causal depthwise conv(K=4) + SiLU + l2norm (q,k)
template <int D>
__global__ __launch_bounds__(D) void conv_silu_n(const float* __restrict__ x, int ldx,
                                                 const float* __restrict__ w,
                                                 float* __restrict__ y,
                                                 int T, int C, int G, float eps) {
  int rb = blockIdx.x;
  int gi = rb % G;
  int bt = rb / G;
  int t = bt % T;
  int b = bt / T;
  int c = gi * D + threadIdx.x;
  const float* wc = w + (size_t)c * KSZ;
  float acc = 0.f;
#pragma unroll
  for (int i = 0; i < KSZ; i++) {
    int tt = t - (KSZ - 1) + i;
    if (tt >= 0) acc = fmaf(x[(size_t)(b * T + tt) * ldx + c], wc[i], acc);
  }
  float val = acc / (1.f + expf(-acc));
  float ss = wave_sum(val * val);
  constexpr int NW = D / 64;
  __shared__ float sred[NW];
  if ((threadIdx.x & 63) == 0) sred[threadIdx.x >> 6] = ss;
  __syncthreads();
  float tot = 0.f;
#pragma unroll
  for (int i = 0; i < NW; i++) tot += sred[i];
  val *= rsqrtf(tot + eps);
  y[(size_t)(b * T + t) * C + c] = val;
}

// ---------------- conv + SiLU for v, output CHUNK-MAJOR: [bh][n][j][dv]
// j = (t&15)*2 + i ; bh = b*4 + h
__global__ __launch_bounds__(256) void conv_silu_v(const float* __restrict__ x, int ldx,
                                                   const float* __restrict__ w,
                                                   float* __restrict__ y, int T) {
  int rb = blockIdx.x;
  int gi = rb % 8;            // i*4 + h
  int bt = rb / 8;
  int t = bt % T;
  int b = bt / T;
  int c = gi * 256 + threadIdx.x;
  const float* wc = w + (size_t)c * KSZ;
  float acc = 0.f;
#pragma unroll
  for (int i = 0; i < KSZ; i++) {
    int tt = t - (KSZ - 1) + i;
    if (tt >= 0) acc = fmaf(x[(size_t)(b * T + tt) * ldx + c], wc[i], acc);
  }
  float val = acc / (1.f + expf(-acc));
  int i = gi >> 2, h = gi & 3;
  int bh = b * 4 + h, n = t >> 4, j = ((t & 15) << 1) + i;
  y[((size_t)(bh * NCHK + n) * UPD + j) * DV + threadIdx.x] = val;
}

// ---------------- pass 1: WY chunk prep. One block per (bh, chunk).
// Solves U = T(beta*v) in place over chunk-major v; W = T(beta*Gamma*k);
// writes E-record {E[j][t], Gq[t], f[j], GC}.
__global__ __launch_bounds__(256) void wy2_prep(const float* __restrict__ q,
                                                const float* __restrict__ k,
                                                const float* __restrict__ beta,
                                                const float* __restrict__ g,
                                                float* __restrict__ vU,
                                                float* __restrict__ W,
                                                float* __restrict__ Erec) {
  const int bh = blockIdx.x & 7;
  const int n = blockIdx.x >> 3;
  const int b = bh >> 2, h = bh & 3;
  const int t0 = n * CH;
  const int tid = threadIdx.x;
  __shared__ float kl[UPD][DK];
  __shared__ float ql[CH][DK];
  __shared__ float L[UPD][UPD];
  __shared__ float bet[UPD];
  __shared__ float pgs[CH];
  // stage k (32x128) and q (16x128)
#pragma unroll
  for (int rr = 0; rr < 16; rr++) {
    int idx = tid + rr * 256, j = idx >> 7, d = idx & 127;
    int t = t0 + (j >> 1), i = j & 1;
    kl[j][d] = k[(size_t)(((b * 1024 + t) * 2 + i) * 4 + h) * 128 + d];
  }
#pragma unroll
  for (int rr = 0; rr < 8; rr++) {
    int idx = tid + rr * 256, t = idx >> 7, d = idx & 127;
    ql[t][d] = q[(size_t)((b * 1024 + t0 + t) * 4 + h) * 128 + d];
  }
  if (tid < UPD) {
    int t = t0 + (tid >> 1), i = tid & 1;
    bet[tid] = beta[(size_t)((b * 1024 + t) * 2 + i) * 4 + h];
  }
  if (tid == 0) {
    float a = 0.f;
    for (int t = 0; t < CH; t++) {
      a += g[(size_t)(b * 1024 + t0 + t) * 4 + h];
      pgs[t] = a;
    }
  }
  __syncthreads();
  // Gram k-k (496 pairs) -> L[j][i] = beta_j * exp(pg[tj]-pg[ti]) * (k_j.k_i)
  for (int p = tid; p < 496; p += 256) {
    int j = (int)((1.0f + sqrtf(1.0f + 8.0f * (float)p)) * 0.5f);
    while (j * (j - 1) / 2 > p) j--;
    while ((j + 1) * j / 2 <= p) j++;
    int i = p - j * (j - 1) / 2;
    float d = 0.f;
    for (int x = 0; x < DK; x++) d = fmaf(kl[j][x], kl[i][x], d);
    L[j][i] = bet[j] * __expf(pgs[j >> 1] - pgs[i >> 1]) * d;
  }
  // q-k dots -> E[j][t] (causal, zero elsewhere)
  float* E = Erec + (size_t)(bh * NCHK + n) * EREC;
  for (int e = tid; e < 512; e += 256) {
    int t = e >> 5, j = e & 31;
    float val = 0.f;
    if ((j >> 1) <= t) {
      float d = 0.f;
      for (int x = 0; x < DK; x++) d = fmaf(ql[t][x], kl[j][x], d);
      val = __expf(pgs[t] - pgs[j >> 1]) * d;
    }
    E[j * 16 + t] = val;
  }
  if (tid < CH) E[512 + tid] = __expf(pgs[tid]);                     // Gq
  if (tid < UPD) E[528 + tid] = __expf(pgs[CH - 1] - pgs[tid >> 1]); // f
  if (tid == 0) E[560] = __expf(pgs[CH - 1]);                        // GC
  __syncthreads();
  // solve U in place over chunk-major v (thread = dv column)
  {
    float u[UPD];
    float* vp = vU + (size_t)(bh * NCHK + n) * (UPD * DV) + tid;
#pragma unroll
    for (int j = 0; j < UPD; j++) {
      float x = bet[j] * vp[j * DV];
#pragma unroll
      for (int i = 0; i < j; i++) x = fmaf(-L[j][i], u[i], x);
      u[j] = x;
      vp[j * DV] = x;
    }
  }
  // solve W (threads 0..127, thread = dk column)
  if (tid < DK) {
    float w[UPD];
    float* wp = W + (size_t)(bh * NCHK + n) * (UPD * DK) + tid;
#pragma unroll
    for (int j = 0; j < UPD; j++) {
      float x = bet[j] * __expf(pgs[j >> 1]) * kl[j][tid];
#pragma unroll
      for (int i = 0; i < j; i++) x = fmaf(-L[j][i], w[i], x);
      w[j] = x;
      wp[j * DK] = x;
    }
  }
}

// ---------------- pass 2: chunked scan, one wave per (b,h,dv-col), XCD-pinned.
// Per chunk: 48 batched dots (one DPP session), c = U - W.s, state fold, lane-split outputs.
__global__ __launch_bounds__(256, 2) void scan_wy2(const float* __restrict__ q,
                                                   const float* __restrict__ k,
                                                   const float* __restrict__ U,
                                                   const float* __restrict__ W,
                                                   const float* __restrict__ Erec,
                                                   float* __restrict__ o) {
  const int lane = threadIdx.x & 63;
  const int wave = __builtin_amdgcn_readfirstlane(threadIdx.x >> 6);
  const int bh = blockIdx.x & 7;
  const int cb = blockIdx.x >> 3;
  const int b = bh >> 2, h = bh & 3;
  const int col = cb * 4 + wave;
  const float2* __restrict__ q2 = (const float2*)q;
  const float2* __restrict__ k2 = (const float2*)k;
  const float2* __restrict__ W2 = (const float2*)W;
  float sx = 0.f, sy = 0.f;

  for (int n = 0; n < NCHK; n++) {
    const float* E = Erec + (size_t)(bh * NCHK + n) * EREC;
    const float2* wp = W2 + (size_t)(bh * NCHK + n) * (UPD * 64);
    const float* up = U + (size_t)(bh * NCHK + n) * (UPD * DV) + col;
    // batched dots vs pre-chunk state
    float r[UPD];
#pragma unroll
    for (int j = 0; j < UPD; j++) {
      float2 wj = wp[j * 64 + lane];
      r[j] = wj.x * sx + wj.y * sy;
    }
    float rq[CH];
#pragma unroll
    for (int t = 0; t < CH; t++) {
      float2 qt = q2[(size_t)((b * 1024 + n * CH + t) * 4 + h) * 64 + lane];
      rq[t] = qt.x * sx + qt.y * sy;
    }
    dpp_reduce(r);
    dpp_reduce(rq);
    // update coefficients (no substitution -- absorbed into U/W)
    float c[UPD];
#pragma unroll
    for (int j = 0; j < UPD; j++) c[j] = up[j * DV] - r[j];
    // state fold to chunk end
    float GC = E[560];
    float nsx = GC * sx, nsy = GC * sy;
#pragma unroll
    for (int j = 0; j < UPD; j++) {
      int t = n * CH + (j >> 1), i = j & 1;
      float2 kj = k2[(size_t)(((b * 1024 + t) * 2 + i) * 4 + h) * 64 + lane];
      float fc = E[528 + j] * c[j];
      nsx = fmaf(fc, kj.x, nsx);
      nsy = fmaf(fc, kj.y, nsy);
    }
    sx = nsx;
    sy = nsy;
    // outputs: lane t in [0,16) computes o_t (static-index select of rq)
    float myrq = rq[0];
#pragma unroll
    for (int t = 1; t < CH; t++) myrq = (lane == t) ? rq[t] : myrq;
    if (lane < CH) {
      float ov = E[512 + lane] * myrq;
#pragma unroll
      for (int j = 0; j < UPD; j++) ov = fmaf(E[j * 16 + lane], c[j], ov);
      o[(size_t)(b * 1024 + n * CH + lane) * NTOT + h * 256 + col] = ov;
    }
  }
}

// ---------------- RMSNorm(o) * w * SiLU(gate); writes dense bf16 [M][1024]
__global__ __launch_bounds__(256) void post_norm_gate(const float* __restrict__ o,
                                                      const float* __restrict__ gate,
                                                      const float* __restrict__ w,
                                                      ushort* __restrict__ obf) {
  int rb = blockIdx.x;  // bt*H + h
  int bt = rb >> 2, h = rb & 3;
  int tid = threadIdx.x;
  size_t ob = (size_t)bt * NTOT + h * 256 + tid;
  float ov = o[ob];
  float ss = wave_sum(ov * ov);
  __shared__ float sred[4];
  if ((tid & 63) == 0) sred[tid >> 6] = ss;
  __syncthreads();
  float tot = sred[0] + sred[1] + sred[2] + sred[3];
  float rms = rsqrtf(tot * (1.f / 256.f) + 1e-5f);
  float gt = gate[(size_t)bt * NTOT + h * 256 + tid];
  float val = ov * rms * w[tid] * (gt / (1.f + expf(-gt)));
  obf[(size_t)bt * HID + h * 256 + tid] = f2bf(val);
}

extern "C" void kernel_launch(void* const* d_in, const int* in_sizes, int n_in,
                              void* d_out, int out_size, void* d_ws, size_t ws_size,
                              hipStream_t stream) {
  const float* hs      = (const float*)d_in[0];
  const float* Wq      = (const float*)d_in[1];
  const float* Wk      = (const float*)d_in[2];
  const float* Wv      = (const float*)d_in[3];
  const float* Wb      = (const float*)d_in[4];
  const float* Wa      = (const float*)d_in[5];
  const float* Wg      = (const float*)d_in[6];
  const float* Wo      = (const float*)d_in[7];
  const float* A_log   = (const float*)d_in[8];
  const float* dt_bias = (const float*)d_in[9];
  const float* wq_conv = (const float*)d_in[10];
  const float* wk_conv = (const float*)d_in[11];
  const float* wv_conv = (const float*)d_in[12];
  const float* o_w     = (const float*)d_in[13];
  float* out = (float*)d_out;

  const int B = 2, T = 1024, M = B * T;

  float* ws    = (float*)d_ws;
  float* qkvg  = ws;                          // M*4608 fp32; cols 0..1023 get o; 3584+ gate
  float* kbuf  = qkvg + (size_t)M * NTOT;     // M*1024 raw k
  float* vbuf  = kbuf + (size_t)M * 1024;     // M*2048 chunk-major v -> U in place
  float* betab = vbuf + (size_t)M * 2048;     // M*8
  float* gb    = betab + (size_t)M * 8;       // M*4 (raw g)
  float* erec  = gb + (size_t)M * 4;          // 512 * 576 = 294,912 floats (1.18MB)
  float* wbuf  = erec + (size_t)512 * EREC;   // 512 * 32 * 128 = 2.10M floats (8.39MB)
  float* qbuf  = out;                         // M*512 scratch in d_out

  // time-disjoint bf16 aliases (dead after projection GEMM):
  ushort* bqkvgT = (ushort*)kbuf;
  ushort* hsb    = (ushort*)(vbuf + (size_t)524288);
  ushort* woT    = (ushort*)kbuf;   // reused again after scan reads k?  NO -- tr_one runs after scan_wy2
  ushort* obf    = (ushort*)vbuf;   // after scan (U dead)

  // casts + fused projections
  cast_hs<<<(M * HID / 4) / 256, 256, 0, stream>>>(hs, hsb);
  tr_pack<<<dim3(NTOT / 32, HID / 32), 256, 0, stream>>>(Wq, Wk, Wv, Wg, bqkvgT);
  gemm_bf16<<<dim3(NTOT / 128, M / 128), 256, 0, stream>>>(hsb, bqkvgT, qkvg, HID, NTOT);
  // beta / raw g
  proj_bg<<<M, 256, 0, stream>>>(hs, Wb, Wa, A_log, dt_bias, betab, gb);
  // conv + SiLU (+ l2norm q,k); v written chunk-major
  conv_silu_n<128><<<M * 4, 128, 0, stream>>>(qkvg + 0, NTOT, wq_conv, qbuf, T, 512, 4, 1e-6f);
  conv_silu_n<128><<<M * 8, 128, 0, stream>>>(qkvg + 512, NTOT, wk_conv, kbuf, T, 1024, 8, 1e-6f);
  conv_silu_v<<<M * 8, 256, 0, stream>>>(qkvg + 1536, NTOT, wv_conv, vbuf, T);
  // pass 1: chunk prep (U in place over vbuf, W, E)
  wy2_prep<<<8 * NCHK, 256, 0, stream>>>(qbuf, kbuf, betab, gb, vbuf, wbuf, erec);
  // pass 2: chunked scan -> o into qkvg cols 0..1023
  scan_wy2<<<512, 256, 0, stream>>>(qbuf, kbuf, vbuf, wbuf, erec, qkvg);
  // epilogue norm/gate -> bf16 obf (vbuf region, dead after scan)
  post_norm_gate<<<M * H, 256, 0, stream>>>(qkvg, qkvg + 3584, o_w, obf);
  // output projection
  tr_one<<<dim3(HID / 32, HID / 32), 256, 0, stream>>>(Wo, woT, HID);
  gemm_bf16<<<dim3(HID / 128, M / 128), 256, 0, stream>>>(obf, woT, out, HID, HID);
}

// Round 10
// 504.597 us; speedup vs baseline: 1.9155x; 1.9155x over previous
//
#include <hip/hip_runtime.h>
#include <cstdint>
#include <cstddef>

#define H 4
#define DK 128
#define DV 256
#define NH 2
#define HID 1024
#define KSZ 4
#define NTOT 4608  // packed projection width: 512 q | 1024 k | 2048 v | 1024 g

typedef __bf16 bfx8 __attribute__((ext_vector_type(8)));
typedef float f32x4 __attribute__((ext_vector_type(4)));
typedef float f32x2 __attribute__((ext_vector_type(2)));

__device__ __forceinline__ float wave_sum(float x) {
#pragma unroll
  for (int off = 1; off < 64; off <<= 1) x += __shfl_xor(x, off, 64);
  return x;
}

__device__ __forceinline__ ushort f2bf(float x) {
  uint u = __float_as_uint(x);
  return (ushort)((u + 0x7fffu + ((u >> 16) & 1u)) >> 16);
}

#define DPP_ADD(x, ctrl) \
  x += __int_as_float(__builtin_amdgcn_update_dpp(0, __float_as_int(x), ctrl, 0xf, 0xf, true))

// three independent full-wave64 sums, DPP chains interleaved for latency hiding
__device__ __forceinline__ void dpp_sum3(float& a, float& b, float& c) {
#define DPP_L(ctrl) DPP_ADD(a, ctrl); DPP_ADD(b, ctrl); DPP_ADD(c, ctrl);
  DPP_L(0x111)  // row_shr:1
  DPP_L(0x112)  // row_shr:2
  DPP_L(0x114)  // row_shr:4
  DPP_L(0x118)  // row_shr:8
  DPP_L(0x142)  // row_bcast:15
  DPP_L(0x143)  // row_bcast:31
#undef DPP_L
  a = __int_as_float(__builtin_amdgcn_readlane(__float_as_int(a), 63));
  b = __int_as_float(__builtin_amdgcn_readlane(__float_as_int(b), 63));
  c = __int_as_float(__builtin_amdgcn_readlane(__float_as_int(c), 63));
}

// ---------------- fp32 -> bf16 cast, 4 elems/thread
__global__ __launch_bounds__(256) void cast_hs(const float* __restrict__ src,
                                               ushort* __restrict__ dst) {
  int i = blockIdx.x * 256 + threadIdx.x;
  float4 v = ((const float4*)src)[i];
  ushort4 o = {f2bf(v.x), f2bf(v.y), f2bf(v.z), f2bf(v.w)};
  ((ushort4*)dst)[i] = o;
}

// ---------------- transpose+cast packed weights: Bt[4608][1024] bf16
__global__ __launch_bounds__(256) void tr_pack(const float* __restrict__ Wq,
                                               const float* __restrict__ Wk,
                                               const float* __restrict__ Wv,
                                               const float* __restrict__ Wg,
                                               ushort* __restrict__ Bt) {
  __shared__ float tile[32][33];
  int n0 = blockIdx.x * 32, k0 = blockIdx.y * 32;
  const float* src;
  int ld, nb;
  if (n0 < 512)       { src = Wq; ld = 512;  nb = n0; }
  else if (n0 < 1536) { src = Wk; ld = 1024; nb = n0 - 512; }
  else if (n0 < 3584) { src = Wv; ld = 2048; nb = n0 - 1536; }
  else                { src = Wg; ld = 1024; nb = n0 - 3584; }
  int tx = threadIdx.x & 31, ty = threadIdx.x >> 5;
#pragma unroll
  for (int i = 0; i < 4; i++)
    tile[ty + i * 8][tx] = src[(size_t)(k0 + ty + i * 8) * ld + nb + tx];
  __syncthreads();
#pragma unroll
  for (int i = 0; i < 4; i++)
    Bt[(size_t)(n0 + ty + i * 8) * 1024 + k0 + tx] = f2bf(tile[tx][ty + i * 8]);
}

// ---------------- transpose+cast single square matrix (Wo)
__global__ __launch_bounds__(256) void tr_one(const float* __restrict__ W,
                                              ushort* __restrict__ Bt, int N) {
  __shared__ float tile[32][33];
  int n0 = blockIdx.x * 32, k0 = blockIdx.y * 32;
  int tx = threadIdx.x & 31, ty = threadIdx.x >> 5;
#pragma unroll
  for (int i = 0; i < 4; i++)
    tile[ty + i * 8][tx] = W[(size_t)(k0 + ty + i * 8) * N + n0 + tx];
  __syncthreads();
#pragma unroll
  for (int i = 0; i < 4; i++)
    Bt[(size_t)(n0 + ty + i * 8) * 1024 + k0 + tx] = f2bf(tile[tx][ty + i * 8]);
}

// ---------------- bf16 MFMA GEMM: C[M,N](fp32, ldc) = A[M,K]bf16 @ Bt[N,K]bf16^T
#define LDP 40
__global__ __launch_bounds__(256) void gemm_bf16(const ushort* __restrict__ A,
                                                 const ushort* __restrict__ Bt,
                                                 float* __restrict__ C,
                                                 int K, int ldc) {
  __shared__ __align__(16) ushort As[128][LDP];
  __shared__ __align__(16) ushort Bs[128][LDP];
  const int tid = threadIdx.x;
  const int lane = tid & 63, wave = tid >> 6;
  const int wr = wave >> 1, wc = wave & 1;
  const int row0 = blockIdx.y * 128, col0 = blockIdx.x * 128;
  const int r = tid >> 1, hf = tid & 1;

  f32x4 acc[4][4];
#pragma unroll
  for (int i = 0; i < 4; i++)
#pragma unroll
    for (int j = 0; j < 4; j++) acc[i][j] = {0.f, 0.f, 0.f, 0.f};

  const int lrow = lane & 15, lk = (lane >> 4) * 8;

  for (int k0 = 0; k0 < K; k0 += 32) {
    const float4* pa = (const float4*)(A + (size_t)(row0 + r) * K + k0 + hf * 16);
    const float4* pb = (const float4*)(Bt + (size_t)(col0 + r) * K + k0 + hf * 16);
    float4 a0 = pa[0], a1 = pa[1];
    float4 b0 = pb[0], b1 = pb[1];
    __syncthreads();
    *(float4*)&As[r][hf * 16] = a0;
    *(float4*)&As[r][hf * 16 + 8] = a1;
    *(float4*)&Bs[r][hf * 16] = b0;
    *(float4*)&Bs[r][hf * 16 + 8] = b1;
    __syncthreads();
    bfx8 af[4], bf[4];
#pragma unroll
    for (int mf = 0; mf < 4; mf++)
      af[mf] = *(const bfx8*)&As[wr * 64 + mf * 16 + lrow][lk];
#pragma unroll
    for (int nf = 0; nf < 4; nf++)
      bf[nf] = *(const bfx8*)&Bs[wc * 64 + nf * 16 + lrow][lk];
#pragma unroll
    for (int mf = 0; mf < 4; mf++)
#pragma unroll
      for (int nf = 0; nf < 4; nf++)
        acc[mf][nf] = __builtin_amdgcn_mfma_f32_16x16x32_bf16(af[mf], bf[nf], acc[mf][nf], 0, 0, 0);
  }
  const int crow = (lane >> 4) * 4, ccol = lane & 15;
#pragma unroll
  for (int mf = 0; mf < 4; mf++)
#pragma unroll
    for (int nf = 0; nf < 4; nf++)
#pragma unroll
      for (int rr = 0; rr < 4; rr++)
        C[(size_t)(row0 + wr * 64 + mf * 16 + crow + rr) * ldc + col0 + wc * 64 + nf * 16 + ccol] =
            acc[mf][nf][rr];
}

// ---------------- beta / gamma tiny projections with fused activations
// g buffer stores gamma = exp(g)
__global__ __launch_bounds__(256) void proj_bg(const float* __restrict__ hs,
                                               const float* __restrict__ Wb,
                                               const float* __restrict__ Wa,
                                               const float* __restrict__ A_log,
                                               const float* __restrict__ dt_bias,
                                               float* __restrict__ beta,
                                               float* __restrict__ g) {
  int row = blockIdx.x;
  int lane = threadIdx.x & 63;
  int wave = threadIdx.x >> 6;
  const float* x = hs + (size_t)row * HID;
  for (int out = wave; out < 12; out += 4) {
    float sum = 0.f;
    if (out < 8) {
      for (int k = lane; k < HID; k += 64) sum = fmaf(x[k], Wb[(size_t)k * 8 + out], sum);
    } else {
      int c = out - 8;
      for (int k = lane; k < HID; k += 64) sum = fmaf(x[k], Wa[(size_t)k * 4 + c], sum);
    }
    sum = wave_sum(sum);
    if (lane == 0) {
      if (out < 8) {
        beta[(size_t)row * 8 + out] = 2.f / (1.f + expf(-sum));
      } else {
        int h = out - 8;
        float xx = sum + dt_bias[h];
        float sp = (xx > 20.f) ? xx : log1pf(expf(xx));
        g[(size_t)row * 4 + h] = expf(-expf(A_log[h]) * sp);  // gamma
      }
    }
  }
}

// ---------------- causal depthwise conv(K=4) + SiLU (+ optional l2norm over D)
template <int D, bool NORM>
__global__ __launch_bounds__(D) void conv_silu(const float* __restrict__ x, int ldx,
                                               const float* __restrict__ w,
                                               float* __restrict__ y,
                                               int T, int C, int G, float eps) {
  int rb = blockIdx.x;
  int gi = rb % G;
  int bt = rb / G;
  int t = bt % T;
  int b = bt / T;
  int c = gi * D + threadIdx.x;
  const float* wc = w + (size_t)c * KSZ;
  float acc = 0.f;
#pragma unroll
  for (int i = 0; i < KSZ; i++) {
    int tt = t - (KSZ - 1) + i;
    if (tt >= 0) acc = fmaf(x[(size_t)(b * T + tt) * ldx + c], wc[i], acc);
  }
  float val = acc / (1.f + expf(-acc));
  if constexpr (NORM) {
    float ss = wave_sum(val * val);
    constexpr int NW = D / 64;
    __shared__ float sred[NW];
    if ((threadIdx.x & 63) == 0) sred[threadIdx.x >> 6] = ss;
    __syncthreads();
    float tot = 0.f;
#pragma unroll
    for (int i = 0; i < NW; i++) tot += sred[i];
    val *= rsqrtf(tot + eps);
  }
  y[(size_t)(b * T + t) * C + c] = val;
}

// ---------------- cross dots + gamma pack: {d01, e0, e1, gamma} per (bt,h)
__global__ __launch_bounds__(256) void cross_dots(const float* __restrict__ q,
                                                  const float* __restrict__ k,
                                                  const float* __restrict__ gam,
                                                  float* __restrict__ dots) {
  int idx = blockIdx.x * 4 + (threadIdx.x >> 6);  // bt*H + h
  int lane = threadIdx.x & 63;
  int bt = idx >> 2, h = idx & 3;
  const float2* q2 = (const float2*)q;
  const float2* k2 = (const float2*)k;
  float2 qq = q2[((size_t)bt * H + h) * 64 + lane];
  float2 ka = k2[((size_t)(bt * NH + 0) * H + h) * 64 + lane];
  float2 kb = k2[((size_t)(bt * NH + 1) * H + h) * 64 + lane];
  float d01 = ka.x * kb.x + ka.y * kb.y;
  float e0 = qq.x * ka.x + qq.y * ka.y;
  float e1 = qq.x * kb.x + qq.y * kb.y;
  dpp_sum3(d01, e0, e1);
  if (lane == 0) {
    float4 o4 = {d01, e0, e1, gam[idx]};
    *(float4*)&dots[(size_t)idx * 4] = o4;
  }
}

// ---------------- sequential gated-delta scan, one wave per (b,h,dv-column)
// XCD-local: bh = blockIdx%8. 4-deep prefetch FIFO with ASM-PINNED loads:
// asm volatile global_load cannot be sunk by the compiler (the failure mode of
// R6-R9: VGPR=52 proved loads were sunk to use, exposing L2 latency per step).
// Counted s_waitcnt vmcnt(24) = 8 loads/slot x 3 younger slots stay in flight.
#define LD1(dst, p, mod) asm volatile("global_load_dword %0, %1, off" mod : "=v"(dst) : "v"(p))
#define LD2(dst, p, mod) asm volatile("global_load_dwordx2 %0, %1, off" mod : "=v"(dst) : "v"(p))
#define LD4(dst, p, mod) asm volatile("global_load_dwordx4 %0, %1, off" mod : "=v"(dst) : "v"(p))

__global__ __launch_bounds__(256, 2) void scan_kernel(const float* __restrict__ q,
                                                      const float* __restrict__ k,
                                                      const float* __restrict__ v,
                                                      const float* __restrict__ beta,
                                                      const float* __restrict__ dots,
                                                      float* __restrict__ o,
                                                      int T) {
  const int lane = threadIdx.x & 63;
  const int wave = __builtin_amdgcn_readfirstlane(threadIdx.x >> 6);
  const int bh = blockIdx.x & 7;   // -> XCD-local
  const int cb = blockIdx.x >> 3;
  const int b = bh >> 2, h = bh & 3;
  const int col = cb * 4 + wave;   // wave-uniform
  const int bT = b * T;

  // rolling byte pointers (advance 1 timestep after each LOADQ)
  const char* kp = (const char*)((const f32x2*)k + (size_t)(bT * 512 + h * 64) + lane);
  const char* qp = (const char*)((const f32x2*)q + (size_t)(bT * 256 + h * 64) + lane);
  const char* vp = (const char*)(v + (size_t)(bT * 2048 + h * 256 + col)) + 2048;  // va=-2048, vb=+2048
  const char* bp = (const char*)(beta + (size_t)(bT * 8 + h));                      // bea=0, beb=+16
  const char* dp = (const char*)(dots + (size_t)(bT * 16 + h * 4));                 // float4 record
  int io_cur = bT * NTOT + h * 256 + col;

  float sx = 0.f, sy = 0.f;

  f32x2 Aka, Akb, Aqq; float Ava, Avb, Abea, Abeb; f32x4 Add;
  f32x2 Bka, Bkb, Bqq; float Bva, Bvb, Bbea, Bbeb; f32x4 Bdd;
  f32x2 Cka, Ckb, Cqq; float Cva, Cvb, Cbea, Cbeb; f32x4 Cdd;
  f32x2 Dka, Dkb, Dqq; float Dva, Dvb, Dbea, Dbeb; f32x4 Ddd;

#define LOADQ(P) { \
    LD2(P##ka, kp, ""); \
    LD2(P##kb, kp, " offset:2048"); \
    LD2(P##qq, qp, ""); \
    LD1(P##va, vp, " offset:-2048"); \
    LD1(P##vb, vp, " offset:2048"); \
    LD1(P##bea, bp, ""); \
    LD1(P##beb, bp, " offset:16"); \
    LD4(P##dd, dp, ""); \
    kp += 4096; qp += 2048; vp += 8192; bp += 32; dp += 64; }

#define STEPQ(P, WAITN) { \
    asm volatile("s_waitcnt vmcnt(" WAITN ")"); \
    __builtin_amdgcn_sched_barrier(0); \
    float gm = P##dd.w; \
    float p0 = P##ka.x * sx + P##ka.y * sy; \
    float p1 = P##kb.x * sx + P##kb.y * sy; \
    float pq = P##qq.x * sx + P##qq.y * sy; \
    dpp_sum3(p0, p1, pq); \
    float gb0 = P##bea * gm, gb1 = P##beb * gm, bd = P##beb * P##dd.x; \
    float t0 = P##bea * P##va, t1 = P##beb * P##vb; \
    float c0 = fmaf(-gb0, p0, t0); \
    float c1 = fmaf(-bd, c0, fmaf(-gb1, p1, t1)); \
    float ov = fmaf(c1, P##dd.z, fmaf(c0, P##dd.y, gm * pq)); \
    sx = fmaf(gm, sx, fmaf(c0, P##ka.x, c1 * P##kb.x)); \
    sy = fmaf(gm, sy, fmaf(c0, P##ka.y, c1 * P##kb.y)); \
    if (lane == 0) o[io_cur] = ov; \
    io_cur += NTOT; }

  LOADQ(A)
  LOADQ(B)
  LOADQ(C)
  LOADQ(D)
  for (int t = 0; t + 4 < T; t += 4) {
    STEPQ(A, "24") LOADQ(A)
    STEPQ(B, "24") LOADQ(B)
    STEPQ(C, "24") LOADQ(C)
    STEPQ(D, "24") LOADQ(D)
  }
  STEPQ(A, "24")
  STEPQ(B, "16")
  STEPQ(C, "8")
  STEPQ(D, "0")
#undef LOADQ
#undef STEPQ
}

// ---------------- RMSNorm(o) * w * SiLU(gate); writes dense bf16 [M][1024]
__global__ __launch_bounds__(256) void post_norm_gate(const float* __restrict__ o,
                                                      const float* __restrict__ gate,
                                                      const float* __restrict__ w,
                                                      ushort* __restrict__ obf) {
  int rb = blockIdx.x;  // bt*H + h
  int bt = rb >> 2, h = rb & 3;
  int tid = threadIdx.x;
  size_t ob = (size_t)bt * NTOT + h * 256 + tid;
  float ov = o[ob];
  float ss = wave_sum(ov * ov);
  __shared__ float sred[4];
  if ((tid & 63) == 0) sred[tid >> 6] = ss;
  __syncthreads();
  float tot = sred[0] + sred[1] + sred[2] + sred[3];
  float rms = rsqrtf(tot * (1.f / 256.f) + 1e-5f);
  float gt = gate[(size_t)bt * NTOT + h * 256 + tid];
  float val = ov * rms * w[tid] * (gt / (1.f + expf(-gt)));
  obf[(size_t)bt * HID + h * 256 + tid] = f2bf(val);
}

extern "C" void kernel_launch(void* const* d_in, const int* in_sizes, int n_in,
                              void* d_out, int out_size, void* d_ws, size_t ws_size,
                              hipStream_t stream) {
  const float* hs      = (const float*)d_in[0];
  const float* Wq      = (const float*)d_in[1];
  const float* Wk      = (const float*)d_in[2];
  const float* Wv      = (const float*)d_in[3];
  const float* Wb      = (const float*)d_in[4];
  const float* Wa      = (const float*)d_in[5];
  const float* Wg      = (const float*)d_in[6];
  const float* Wo      = (const float*)d_in[7];
  const float* A_log   = (const float*)d_in[8];
  const float* dt_bias = (const float*)d_in[9];
  const float* wq_conv = (const float*)d_in[10];
  const float* wk_conv = (const float*)d_in[11];
  const float* wv_conv = (const float*)d_in[12];
  const float* o_w     = (const float*)d_in[13];
  float* out = (float*)d_out;

  const int B = 2, T = 1024, M = B * T;

  float* ws    = (float*)d_ws;
  float* qkvg  = ws;                          // M*4608 fp32; cols 0..1023 reused for o
  float* kbuf  = qkvg + (size_t)M * NTOT;     // M*1024 fp32
  float* vbuf  = kbuf + (size_t)M * 1024;     // M*2048 fp32
  float* betab = vbuf + (size_t)M * 2048;     // M*8
  float* gb    = betab + (size_t)M * 8;       // M*4 (gamma = exp(g))
  float* dotsb = gb + (size_t)M * 4;          // M*H*4
  float* qbuf  = out;                         // M*512 scratch in d_out; overwritten at end

  // time-disjoint bf16 aliases inside kbuf/vbuf regions:
  ushort* bqkvgT = (ushort*)kbuf;
  ushort* hsb    = (ushort*)(vbuf + (size_t)524288);  // vbuf + 2MB
  ushort* woT = (ushort*)kbuf;
  ushort* obf = (ushort*)vbuf;

  // casts
  cast_hs<<<(M * HID / 4) / 256, 256, 0, stream>>>(hs, hsb);
  tr_pack<<<dim3(NTOT / 32, HID / 32), 256, 0, stream>>>(Wq, Wk, Wv, Wg, bqkvgT);
  // fused projections (bf16 MFMA) -> packed fp32 [M,4608]
  gemm_bf16<<<dim3(NTOT / 128, M / 128), 256, 0, stream>>>(hsb, bqkvgT, qkvg, HID, NTOT);
  // beta / gamma
  proj_bg<<<M, 256, 0, stream>>>(hs, Wb, Wa, A_log, dt_bias, betab, gb);
  // conv + SiLU (+ l2norm for q,k)
  conv_silu<128, true><<<M * 4, 128, 0, stream>>>(qkvg + 0, NTOT, wq_conv, qbuf, T, 512, 4, 1e-6f);
  conv_silu<128, true><<<M * 8, 128, 0, stream>>>(qkvg + 512, NTOT, wk_conv, kbuf, T, 1024, 8, 1e-6f);
  conv_silu<256, false><<<M * 8, 256, 0, stream>>>(qkvg + 1536, NTOT, wv_conv, vbuf, T, 2048, 8, 1e-6f);
  // cross dots + gamma pack
  cross_dots<<<M * H / 4, 256, 0, stream>>>(qbuf, kbuf, gb, dotsb);
  // scan: o written strided into qkvg cols 0..1023
  scan_kernel<<<512, 256, 0, stream>>>(qbuf, kbuf, vbuf, betab, dotsb, qkvg, T);
  // epilogue norm/gate -> dense bf16 obf (vbuf region, dead after scan)
  post_norm_gate<<<M * H, 256, 0, stream>>>(qkvg, qkvg + 3584, o_w, obf);
  // output projection (bf16 MFMA)
  tr_one<<<dim3(HID / 32, HID / 32), 256, 0, stream>>>(Wo, woT, HID);
  gemm_bf16<<<dim3(HID / 128, M / 128), 256, 0, stream>>>(obf, woT, out, HID, HID);
}

// Round 13
// 501.670 us; speedup vs baseline: 1.9267x; 1.0058x over previous
//
#include <hip/hip_runtime.h>
#include <cstdint>
#include <cstddef>

#define H 4
#define DK 128
#define DV 256
#define NH 2
#define HID 1024
#define KSZ 4
#define NTOT 4608  // packed projection width: 512 q | 1024 k | 2048 v | 1024 g

typedef __bf16 bfx8 __attribute__((ext_vector_type(8)));
typedef float f32x4 __attribute__((ext_vector_type(4)));

__device__ __forceinline__ float wave_sum(float x) {
#pragma unroll
  for (int off = 1; off < 64; off <<= 1) x += __shfl_xor(x, off, 64);
  return x;
}

__device__ __forceinline__ ushort f2bf(float x) {
  uint u = __float_as_uint(x);
  return (ushort)((u + 0x7fffu + ((u >> 16) & 1u)) >> 16);
}

#define DPP_ADD(x, ctrl) \
  x += __int_as_float(__builtin_amdgcn_update_dpp(0, __float_as_int(x), ctrl, 0xf, 0xf, true))

// N independent full-wave64 sums, interleaved DPP chains; results uniform via readlane(63)
template <int N>
__device__ __forceinline__ void dpp_reduce(float (&d)[N]) {
#pragma unroll
  for (int i = 0; i < N; i++) DPP_ADD(d[i], 0x111);
#pragma unroll
  for (int i = 0; i < N; i++) DPP_ADD(d[i], 0x112);
#pragma unroll
  for (int i = 0; i < N; i++) DPP_ADD(d[i], 0x114);
#pragma unroll
  for (int i = 0; i < N; i++) DPP_ADD(d[i], 0x118);
#pragma unroll
  for (int i = 0; i < N; i++) DPP_ADD(d[i], 0x142);
#pragma unroll
  for (int i = 0; i < N; i++) DPP_ADD(d[i], 0x143);
#pragma unroll
  for (int i = 0; i < N; i++)
    d[i] = __int_as_float(__builtin_amdgcn_readlane(__float_as_int(d[i]), 63));
}

// ---------------- fp32 -> bf16 cast
__global__ __launch_bounds__(256) void cast_hs(const float* __restrict__ src,
                                               ushort* __restrict__ dst) {
  int i = blockIdx.x * 256 + threadIdx.x;
  float4 v = ((const float4*)src)[i];
  ushort4 o = {f2bf(v.x), f2bf(v.y), f2bf(v.z), f2bf(v.w)};
  ((ushort4*)dst)[i] = o;
}

// ---------------- transpose+cast packed weights
__global__ __launch_bounds__(256) void tr_pack(const float* __restrict__ Wq,
                                               const float* __restrict__ Wk,
                                               const float* __restrict__ Wv,
                                               const float* __restrict__ Wg,
                                               ushort* __restrict__ Bt) {
  __shared__ float tile[32][33];
  int n0 = blockIdx.x * 32, k0 = blockIdx.y * 32;
  const float* src;
  int ld, nb;
  if (n0 < 512)       { src = Wq; ld = 512;  nb = n0; }
  else if (n0 < 1536) { src = Wk; ld = 1024; nb = n0 - 512; }
  else if (n0 < 3584) { src = Wv; ld = 2048; nb = n0 - 1536; }
  else                { src = Wg; ld = 1024; nb = n0 - 3584; }
  int tx = threadIdx.x & 31, ty = threadIdx.x >> 5;
#pragma unroll
  for (int i = 0; i < 4; i++)
    tile[ty + i * 8][tx] = src[(size_t)(k0 + ty + i * 8) * ld + nb + tx];
  __syncthreads();
#pragma unroll
  for (int i = 0; i < 4; i++)
    Bt[(size_t)(n0 + ty + i * 8) * 1024 + k0 + tx] = f2bf(tile[tx][ty + i * 8]);
}

__global__ __launch_bounds__(256) void tr_one(const float* __restrict__ W,
                                              ushort* __restrict__ Bt, int N) {
  __shared__ float tile[32][33];
  int n0 = blockIdx.x * 32, k0 = blockIdx.y * 32;
  int tx = threadIdx.x & 31, ty = threadIdx.x >> 5;
#pragma unroll
  for (int i = 0; i < 4; i++)
    tile[ty + i * 8][tx] = W[(size_t)(k0 + ty + i * 8) * N + n0 + tx];
  __syncthreads();
#pragma unroll
  for (int i = 0; i < 4; i++)
    Bt[(size_t)(n0 + ty + i * 8) * 1024 + k0 + tx] = f2bf(tile[tx][ty + i * 8]);
}

// ---------------- bf16 MFMA GEMM
#define LDP 40
__global__ __launch_bounds__(256) void gemm_bf16(const ushort* __restrict__ A,
                                                 const ushort* __restrict__ Bt,
                                                 float* __restrict__ C,
                                                 int K, int ldc) {
  __shared__ __align__(16) ushort As[128][LDP];
  __shared__ __align__(16) ushort Bs[128][LDP];
  const int tid = threadIdx.x;
  const int lane = tid & 63, wave = tid >> 6;
  const int wr = wave >> 1, wc = wave & 1;
  const int row0 = blockIdx.y * 128, col0 = blockIdx.x * 128;
  const int r = tid >> 1, hf = tid & 1;

  f32x4 acc[4][4];
#pragma unroll
  for (int i = 0; i < 4; i++)
#pragma unroll
    for (int j = 0; j < 4; j++) acc[i][j] = {0.f, 0.f, 0.f, 0.f};

  const int lrow = lane & 15, lk = (lane >> 4) * 8;

  for (int k0 = 0; k0 < K; k0 += 32) {
    const float4* pa = (const float4*)(A + (size_t)(row0 + r) * K + k0 + hf * 16);
    const float4* pb = (const float4*)(Bt + (size_t)(col0 + r) * K + k0 + hf * 16);
    float4 a0 = pa[0], a1 = pa[1];
    float4 b0 = pb[0], b1 = pb[1];
    __syncthreads();
    *(float4*)&As[r][hf * 16] = a0;
    *(float4*)&As[r][hf * 16 + 8] = a1;
    *(float4*)&Bs[r][hf * 16] = b0;
    *(float4*)&Bs[r][hf * 16 + 8] = b1;
    __syncthreads();
    bfx8 af[4], bf[4];
#pragma unroll
    for (int mf = 0; mf < 4; mf++)
      af[mf] = *(const bfx8*)&As[wr * 64 + mf * 16 + lrow][lk];
#pragma unroll
    for (int nf = 0; nf < 4; nf++)
      bf[nf] = *(const bfx8*)&Bs[wc * 64 + nf * 16 + lrow][lk];
#pragma unroll
    for (int mf = 0; mf < 4; mf++)
#pragma unroll
      for (int nf = 0; nf < 4; nf++)
        acc[mf][nf] = __builtin_amdgcn_mfma_f32_16x16x32_bf16(af[mf], bf[nf], acc[mf][nf], 0, 0, 0);
  }
  const int crow = (lane >> 4) * 4, ccol = lane & 15;
#pragma unroll
  for (int mf = 0; mf < 4; mf++)
#pragma unroll
    for (int nf = 0; nf < 4; nf++)
#pragma unroll
      for (int rr = 0; rr < 4; rr++)
        C[(size_t)(row0 + wr * 64 + mf * 16 + crow + rr) * ldc + col0 + wc * 64 + nf * 16 + ccol] =
            acc[mf][nf][rr];
}

// ---------------- beta / gamma tiny projections (gamma = exp(g))
__global__ __launch_bounds__(256) void proj_bg(const float* __restrict__ hs,
                                               const float* __restrict__ Wb,
                                               const float* __restrict__ Wa,
                                               const float* __restrict__ A_log,
                                               const float* __restrict__ dt_bias,
                                               float* __restrict__ beta,
                                               float* __restrict__ g) {
  int row = blockIdx.x;
  int lane = threadIdx.x & 63;
  int wave = threadIdx.x >> 6;
  const float* x = hs + (size_t)row * HID;
  for (int out = wave; out < 12; out += 4) {
    float sum = 0.f;
    if (out < 8) {
      for (int k = lane; k < HID; k += 64) sum = fmaf(x[k], Wb[(size_t)k * 8 + out], sum);
    } else {
      int c = out - 8;
      for (int k = lane; k < HID; k += 64) sum = fmaf(x[k], Wa[(size_t)k * 4 + c], sum);
    }
    sum = wave_sum(sum);
    if (lane == 0) {
      if (out < 8) {
        beta[(size_t)row * 8 + out] = 2.f / (1.f + expf(-sum));
      } else {
        int h = out - 8;
        float xx = sum + dt_bias[h];
        float sp = (xx > 20.f) ? xx : log1pf(expf(xx));
        g[(size_t)row * 4 + h] = expf(-expf(A_log[h]) * sp);  // gamma
      }
    }
  }
}

// ---------------- conv+SiLU+l2norm for q -> pair-interleaved layout
// qbuf2[((b*512+tp)*4+h)*256 + (d>>1)*4 + (d&1) + (t&1)*2]
__global__ __launch_bounds__(128) void conv_q(const float* __restrict__ x, int ldx,
                                              const float* __restrict__ w,
                                              float* __restrict__ y, int T) {
  int rb = blockIdx.x;
  int h = rb % 4;
  int bt = rb / 4;
  int t = bt % T;
  int b = bt / T;
  int d = threadIdx.x;
  int c = h * 128 + d;
  const float* wc = w + (size_t)c * KSZ;
  float acc = 0.f;
#pragma unroll
  for (int i = 0; i < KSZ; i++) {
    int tt = t - (KSZ - 1) + i;
    if (tt >= 0) acc = fmaf(x[(size_t)(b * T + tt) * ldx + c], wc[i], acc);
  }
  float val = acc / (1.f + expf(-acc));
  float ss = wave_sum(val * val);
  __shared__ float sred[2];
  if ((threadIdx.x & 63) == 0) sred[threadIdx.x >> 6] = ss;
  __syncthreads();
  val *= rsqrtf(sred[0] + sred[1] + 1e-6f);
  y[((size_t)(b * 512 + (t >> 1)) * 4 + h) * 256 + (d >> 1) * 4 + (d & 1) + (t & 1) * 2] = val;
}

// ---------------- conv+SiLU+l2norm for k -> copy-interleaved layout
// kbuf2[((b*T+t)*4+h)*256 + (d>>1)*4 + (d&1) + i*2]
__global__ __launch_bounds__(128) void conv_k(const float* __restrict__ x, int ldx,
                                              const float* __restrict__ w,
                                              float* __restrict__ y, int T) {
  int rb = blockIdx.x;
  int gi = rb % 8;  // i*4 + h
  int bt = rb / 8;
  int t = bt % T;
  int b = bt / T;
  int i = gi >> 2, h = gi & 3;
  int d = threadIdx.x;
  int c = i * 512 + h * 128 + d;
  const float* wc = w + (size_t)c * KSZ;
  float acc = 0.f;
#pragma unroll
  for (int kk = 0; kk < KSZ; kk++) {
    int tt = t - (KSZ - 1) + kk;
    if (tt >= 0) acc = fmaf(x[(size_t)(b * T + tt) * ldx + c], wc[kk], acc);
  }
  float val = acc / (1.f + expf(-acc));
  float ss = wave_sum(val * val);
  __shared__ float sred[2];
  if ((threadIdx.x & 63) == 0) sred[threadIdx.x >> 6] = ss;
  __syncthreads();
  val *= rsqrtf(sred[0] + sred[1] + 1e-6f);
  y[((size_t)(b * T + t) * 4 + h) * 256 + (d >> 1) * 4 + (d & 1) + i * 2] = val;
}

// ---------------- conv+SiLU for v -> pair-major layout
// vbuf2[((b*512+tp)*4+h)*1024 + d*4 + (t&1)*2 + i]
__global__ __launch_bounds__(256) void conv_v(const float* __restrict__ x, int ldx,
                                              const float* __restrict__ w,
                                              float* __restrict__ y, int T) {
  int rb = blockIdx.x;
  int gi = rb % 8;  // i*4 + h
  int bt = rb / 8;
  int t = bt % T;
  int b = bt / T;
  int i = gi >> 2, h = gi & 3;
  int d = threadIdx.x;
  int c = i * 1024 + h * 256 + d;
  const float* wc = w + (size_t)c * KSZ;
  float acc = 0.f;
#pragma unroll
  for (int kk = 0; kk < KSZ; kk++) {
    int tt = t - (KSZ - 1) + kk;
    if (tt >= 0) acc = fmaf(x[(size_t)(b * T + tt) * ldx + c], wc[kk], acc);
  }
  float val = acc / (1.f + expf(-acc));
  y[((size_t)(b * 512 + (t >> 1)) * 4 + h) * 1024 + d * 4 + (t & 1) * 2 + i] = val;
}

// ---------------- 2-step coefficient records (24 floats per (b,tp,h))
// rec = {A0,A1,B10,gt | A2,B20,B21,gt1 | A3,B30,B31,B32 | E0,E1,G2,b0 | F0,F1,F2,F3 | b1,b2,b3,0}
__global__ __launch_bounds__(256) void cross_dots2(const float* __restrict__ kbuf2,
                                                   const float* __restrict__ qbuf2,
                                                   const float* __restrict__ beta,
                                                   const float* __restrict__ gam,
                                                   float* __restrict__ rec) {
  int idx = blockIdx.x * 4 + (threadIdx.x >> 6);  // (b*512+tp)*4 + h
  int lane = threadIdx.x & 63;
  int h = idx & 3, tp = (idx >> 2) & 511, b = idx >> 11;
  int t = 2 * tp;
  const float4 kA = *(const float4*)&kbuf2[((size_t)(b * 1024 + t) * 4 + h) * 256 + lane * 4];
  const float4 kB = *(const float4*)&kbuf2[((size_t)(b * 1024 + t + 1) * 4 + h) * 256 + lane * 4];
  const float4 qv = *(const float4*)&qbuf2[(size_t)idx * 256 + lane * 4];
  float d[12];
  d[0] = kA.z * kA.x + kA.w * kA.y;   // d10
  d[1] = kB.x * kA.x + kB.y * kA.y;   // d20
  d[2] = kB.x * kA.z + kB.y * kA.w;   // d21
  d[3] = kB.z * kA.x + kB.w * kA.y;   // d30
  d[4] = kB.z * kA.z + kB.w * kA.w;   // d31
  d[5] = kB.z * kB.x + kB.w * kB.y;   // d32
  d[6] = qv.x * kA.x + qv.y * kA.y;   // e00 = qt.k0
  d[7] = qv.x * kA.z + qv.y * kA.w;   // e01 = qt.k1
  d[8] = qv.z * kA.x + qv.w * kA.y;   // e10 = qt1.k0
  d[9] = qv.z * kA.z + qv.w * kA.w;   // e11 = qt1.k1
  d[10] = qv.z * kB.x + qv.w * kB.y;  // e12 = qt1.k2
  d[11] = qv.z * kB.z + qv.w * kB.w;  // e13 = qt1.k3
  dpp_reduce(d);
  int bt = b * 1024 + t;
  float b0 = beta[(size_t)(bt * 2 + 0) * 4 + h];
  float b1 = beta[(size_t)(bt * 2 + 1) * 4 + h];
  float b2 = beta[(size_t)(bt * 2 + 2) * 4 + h];
  float b3 = beta[(size_t)(bt * 2 + 3) * 4 + h];
  float gt = gam[(size_t)bt * 4 + h];
  float gt1 = gam[(size_t)(bt + 1) * 4 + h];
  if (lane == 0) {
    float G2 = gt * gt1;
    float4* rp = (float4*)&rec[(size_t)idx * 24];
    rp[0] = {b0 * gt, b1 * gt, b1 * d[0], gt};
    rp[1] = {b2 * G2, b2 * gt1 * d[1], b2 * gt1 * d[2], gt1};
    rp[2] = {b3 * G2, b3 * gt1 * d[3], b3 * gt1 * d[4], b3 * d[5]};
    rp[3] = {d[6], d[7], G2, b0};
    rp[4] = {gt1 * d[8], gt1 * d[9], d[10], d[11]};
    rp[5] = {b1, b2, b3, 0.f};
  }
}

// ---------------- 2-step batched gated-delta scan, one wave per (b,h,dv-column)
// PLAIN-C++ loads this round (isolation build): R11/R12's asm-pinned FIFO failed
// correctness twice with verified algebra/layout/sync — suspect register-copy
// hazard on in-flight asm load dests (guide rule #18 class). Named-slot depth-2
// FIFO in plain C++ (the R6-R8 always-correct pattern). If THIS fails, the
// algebra/layout is guilty; if it passes, asm was.
__global__ __launch_bounds__(256, 2) void scan2(const float4* __restrict__ kb,
                                                const float4* __restrict__ qb,
                                                const float4* __restrict__ vb,
                                                const float4* __restrict__ rb,
                                                float* __restrict__ o) {
  const int lane = threadIdx.x & 63;
  const int wave = __builtin_amdgcn_readfirstlane(threadIdx.x >> 6);
  const int bh = blockIdx.x & 7;   // XCD-local
  const int cb = blockIdx.x >> 3;
  const int b = bh >> 2, h = bh & 3;
  const int col = cb * 4 + wave;

  // float4-unit bases (pair stride: k 512, q 256, v 1024, rec 24)
  const float4* kp = kb + ((size_t)(b * 1024) * 4 + h) * 64 + lane;
  const float4* qp = qb + ((size_t)(b * 512) * 4 + h) * 64 + lane;
  const float4* vp = vb + ((size_t)(b * 512) * 4 + h) * 256 + col;
  const float4* rp = rb + ((size_t)(b * 512) * 4 + h) * 6;
  size_t io = (size_t)(b * 1024) * NTOT + h * 256 + col;

  float sx = 0.f, sy = 0.f;

  float4 AkA, AkB, Aqv, Avv, AR0, AR1, AR2, AR3, AR4, AR5;
  float4 BkA, BkB, Bqv, Bvv, BR0, BR1, BR2, BR3, BR4, BR5;

#define LOADQ(P, n) { \
    P##kA = kp[(size_t)(n)*512]; \
    P##kB = kp[(size_t)(n)*512 + 256]; \
    P##qv = qp[(size_t)(n)*256]; \
    P##vv = vp[(size_t)(n)*1024]; \
    P##R0 = rp[(size_t)(n)*24 + 0]; \
    P##R1 = rp[(size_t)(n)*24 + 1]; \
    P##R2 = rp[(size_t)(n)*24 + 2]; \
    P##R3 = rp[(size_t)(n)*24 + 3]; \
    P##R4 = rp[(size_t)(n)*24 + 4]; \
    P##R5 = rp[(size_t)(n)*24 + 5]; }

#define STEPQ(P) { \
    float r[6]; \
    r[0] = P##kA.x * sx + P##kA.y * sy; \
    r[1] = P##kA.z * sx + P##kA.w * sy; \
    r[2] = P##kB.x * sx + P##kB.y * sy; \
    r[3] = P##kB.z * sx + P##kB.w * sy; \
    r[4] = P##qv.x * sx + P##qv.y * sy; \
    r[5] = P##qv.z * sx + P##qv.w * sy; \
    dpp_reduce(r); \
    float c0 = fmaf(-P##R0.x, r[0], P##R3.w * P##vv.x); \
    float c1 = fmaf(-P##R0.z, c0, fmaf(-P##R0.y, r[1], P##R5.x * P##vv.y)); \
    float c2 = fmaf(-P##R1.z, c1, fmaf(-P##R1.y, c0, fmaf(-P##R1.x, r[2], P##R5.y * P##vv.z))); \
    float c3 = fmaf(-P##R2.w, c2, fmaf(-P##R2.z, c1, fmaf(-P##R2.y, c0, \
               fmaf(-P##R2.x, r[3], P##R5.z * P##vv.w)))); \
    float ot = fmaf(P##R3.y, c1, fmaf(P##R3.x, c0, P##R0.w * r[4])); \
    float ot1 = fmaf(P##R4.w, c3, fmaf(P##R4.z, c2, fmaf(P##R4.y, c1, \
                fmaf(P##R4.x, c0, P##R3.z * r[5])))); \
    float g0 = P##R1.w * c0, g1 = P##R1.w * c1; \
    sx = fmaf(c3, P##kB.z, fmaf(c2, P##kB.x, fmaf(g1, P##kA.z, fmaf(g0, P##kA.x, P##R3.z * sx)))); \
    sy = fmaf(c3, P##kB.w, fmaf(c2, P##kB.y, fmaf(g1, P##kA.w, fmaf(g0, P##kA.y, P##R3.z * sy)))); \
    if (lane == 0) { o[io] = ot; o[io + NTOT] = ot1; } \
    io += 2 * NTOT; }

  LOADQ(A, 0)
  LOADQ(B, 1)
  int n = 0;
  for (; n + 2 < 512; n += 2) {
    STEPQ(A) LOADQ(A, n + 2)
    STEPQ(B) LOADQ(B, n + 3)
  }
  STEPQ(A)
  STEPQ(B)
#undef LOADQ
#undef STEPQ
}

// ---------------- RMSNorm(o) * w * SiLU(gate); writes dense bf16 [M][1024]
__global__ __launch_bounds__(256) void post_norm_gate(const float* __restrict__ o,
                                                      const float* __restrict__ gate,
                                                      const float* __restrict__ w,
                                                      ushort* __restrict__ obf) {
  int rb = blockIdx.x;
  int bt = rb >> 2, h = rb & 3;
  int tid = threadIdx.x;
  size_t ob = (size_t)bt * NTOT + h * 256 + tid;
  float ov = o[ob];
  float ss = wave_sum(ov * ov);
  __shared__ float sred[4];
  if ((tid & 63) == 0) sred[tid >> 6] = ss;
  __syncthreads();
  float tot = sred[0] + sred[1] + sred[2] + sred[3];
  float rms = rsqrtf(tot * (1.f / 256.f) + 1e-5f);
  float gt = gate[(size_t)bt * NTOT + h * 256 + tid];
  float val = ov * rms * w[tid] * (gt / (1.f + expf(-gt)));
  obf[(size_t)bt * HID + h * 256 + tid] = f2bf(val);
}

extern "C" void kernel_launch(void* const* d_in, const int* in_sizes, int n_in,
                              void* d_out, int out_size, void* d_ws, size_t ws_size,
                              hipStream_t stream) {
  const float* hs      = (const float*)d_in[0];
  const float* Wq      = (const float*)d_in[1];
  const float* Wk      = (const float*)d_in[2];
  const float* Wv      = (const float*)d_in[3];
  const float* Wb      = (const float*)d_in[4];
  const float* Wa      = (const float*)d_in[5];
  const float* Wg      = (const float*)d_in[6];
  const float* Wo      = (const float*)d_in[7];
  const float* A_log   = (const float*)d_in[8];
  const float* dt_bias = (const float*)d_in[9];
  const float* wq_conv = (const float*)d_in[10];
  const float* wk_conv = (const float*)d_in[11];
  const float* wv_conv = (const float*)d_in[12];
  const float* o_w     = (const float*)d_in[13];
  float* out = (float*)d_out;

  const int B = 2, T = 1024, M = B * T;

  float* ws    = (float*)d_ws;
  float* qkvg  = ws;                          // M*4608 fp32; cols 0..1023 get o; 3584+ gate
  float* kbuf  = qkvg + (size_t)M * NTOT;     // M*1024 (k interleaved)
  float* vbuf  = kbuf + (size_t)M * 1024;     // M*2048 (v pair-major)
  float* betab = vbuf + (size_t)M * 2048;     // M*8
  float* gb    = betab + (size_t)M * 8;       // M*4 (gamma)
  float* recb  = gb + (size_t)M * 4;          // 4096*24 floats
  float* qbuf  = out;                         // M*512 scratch (q pair-interleaved)

  // time-disjoint bf16 aliases in kbuf/vbuf regions:
  ushort* bqkvgT = (ushort*)kbuf;
  ushort* hsb    = (ushort*)(vbuf + (size_t)524288);  // vbuf + 2MB
  ushort* woT = (ushort*)kbuf;
  ushort* obf = (ushort*)vbuf;

  // casts + projections
  cast_hs<<<(M * HID / 4) / 256, 256, 0, stream>>>(hs, hsb);
  tr_pack<<<dim3(NTOT / 32, HID / 32), 256, 0, stream>>>(Wq, Wk, Wv, Wg, bqkvgT);
  gemm_bf16<<<dim3(NTOT / 128, M / 128), 256, 0, stream>>>(hsb, bqkvgT, qkvg, HID, NTOT);
  proj_bg<<<M, 256, 0, stream>>>(hs, Wb, Wa, A_log, dt_bias, betab, gb);
  // conv + SiLU (+ l2norm q,k) into scan-friendly layouts
  conv_q<<<M * 4, 128, 0, stream>>>(qkvg + 0, NTOT, wq_conv, qbuf, T);
  conv_k<<<M * 8, 128, 0, stream>>>(qkvg + 512, NTOT, wk_conv, kbuf, T);
  conv_v<<<M * 8, 256, 0, stream>>>(qkvg + 1536, NTOT, wv_conv, vbuf, T);
  // 2-step coefficient records
  cross_dots2<<<M * H / 8, 256, 0, stream>>>(kbuf, qbuf, betab, gb, recb);
  // batched scan -> o into qkvg cols 0..1023
  scan2<<<512, 256, 0, stream>>>((const float4*)kbuf, (const float4*)qbuf,
                                 (const float4*)vbuf, (const float4*)recb, qkvg);
  // epilogue + output projection
  post_norm_gate<<<M * H, 256, 0, stream>>>(qkvg, qkvg + 3584, o_w, obf);
  tr_one<<<dim3(HID / 32, HID / 32), 256, 0, stream>>>(Wo, woT, HID);
  gemm_bf16<<<dim3(HID / 128, M / 128), 256, 0, stream>>>(obf, woT, out, HID, HID);
}

// Round 14
// 428.469 us; speedup vs baseline: 2.2559x; 1.1708x over previous
//
#include <hip/hip_runtime.h>
#include <cstdint>
#include <cstddef>

#define H 4
#define DK 128
#define DV 256
#define NH 2
#define HID 1024
#define KSZ 4
#define NTOT 4608  // packed projection width: 512 q | 1024 k | 2048 v | 1024 g

typedef __bf16 bfx8 __attribute__((ext_vector_type(8)));
typedef float f32x4 __attribute__((ext_vector_type(4)));

__device__ __forceinline__ float wave_sum(float x) {
#pragma unroll
  for (int off = 1; off < 64; off <<= 1) x += __shfl_xor(x, off, 64);
  return x;
}

__device__ __forceinline__ ushort f2bf(float x) {
  uint u = __float_as_uint(x);
  return (ushort)((u + 0x7fffu + ((u >> 16) & 1u)) >> 16);
}

#define DPP_ADD(x, ctrl) \
  x += __int_as_float(__builtin_amdgcn_update_dpp(0, __float_as_int(x), ctrl, 0xf, 0xf, true))

// N independent full-wave64 sums, interleaved DPP chains; results uniform via readlane(63)
template <int N>
__device__ __forceinline__ void dpp_reduce(float (&d)[N]) {
#pragma unroll
  for (int i = 0; i < N; i++) DPP_ADD(d[i], 0x111);
#pragma unroll
  for (int i = 0; i < N; i++) DPP_ADD(d[i], 0x112);
#pragma unroll
  for (int i = 0; i < N; i++) DPP_ADD(d[i], 0x114);
#pragma unroll
  for (int i = 0; i < N; i++) DPP_ADD(d[i], 0x118);
#pragma unroll
  for (int i = 0; i < N; i++) DPP_ADD(d[i], 0x142);
#pragma unroll
  for (int i = 0; i < N; i++) DPP_ADD(d[i], 0x143);
#pragma unroll
  for (int i = 0; i < N; i++)
    d[i] = __int_as_float(__builtin_amdgcn_readlane(__float_as_int(d[i]), 63));
}

// ---------------- fp32 -> bf16 cast
__global__ __launch_bounds__(256) void cast_hs(const float* __restrict__ src,
                                               ushort* __restrict__ dst) {
  int i = blockIdx.x * 256 + threadIdx.x;
  float4 v = ((const float4*)src)[i];
  ushort4 o = {f2bf(v.x), f2bf(v.y), f2bf(v.z), f2bf(v.w)};
  ((ushort4*)dst)[i] = o;
}

// ---------------- transpose+cast packed weights
__global__ __launch_bounds__(256) void tr_pack(const float* __restrict__ Wq,
                                               const float* __restrict__ Wk,
                                               const float* __restrict__ Wv,
                                               const float* __restrict__ Wg,
                                               ushort* __restrict__ Bt) {
  __shared__ float tile[32][33];
  int n0 = blockIdx.x * 32, k0 = blockIdx.y * 32;
  const float* src;
  int ld, nb;
  if (n0 < 512)       { src = Wq; ld = 512;  nb = n0; }
  else if (n0 < 1536) { src = Wk; ld = 1024; nb = n0 - 512; }
  else if (n0 < 3584) { src = Wv; ld = 2048; nb = n0 - 1536; }
  else                { src = Wg; ld = 1024; nb = n0 - 3584; }
  int tx = threadIdx.x & 31, ty = threadIdx.x >> 5;
#pragma unroll
  for (int i = 0; i < 4; i++)
    tile[ty + i * 8][tx] = src[(size_t)(k0 + ty + i * 8) * ld + nb + tx];
  __syncthreads();
#pragma unroll
  for (int i = 0; i < 4; i++)
    Bt[(size_t)(n0 + ty + i * 8) * 1024 + k0 + tx] = f2bf(tile[tx][ty + i * 8]);
}

__global__ __launch_bounds__(256) void tr_one(const float* __restrict__ W,
                                              ushort* __restrict__ Bt, int N) {
  __shared__ float tile[32][33];
  int n0 = blockIdx.x * 32, k0 = blockIdx.y * 32;
  int tx = threadIdx.x & 31, ty = threadIdx.x >> 5;
#pragma unroll
  for (int i = 0; i < 4; i++)
    tile[ty + i * 8][tx] = W[(size_t)(k0 + ty + i * 8) * N + n0 + tx];
  __syncthreads();
#pragma unroll
  for (int i = 0; i < 4; i++)
    Bt[(size_t)(n0 + ty + i * 8) * 1024 + k0 + tx] = f2bf(tile[tx][ty + i * 8]);
}

// ---------------- bf16 MFMA GEMM
#define LDP 40
__global__ __launch_bounds__(256) void gemm_bf16(const ushort* __restrict__ A,
                                                 const ushort* __restrict__ Bt,
                                                 float* __restrict__ C,
                                                 int K, int ldc) {
  __shared__ __align__(16) ushort As[128][LDP];
  __shared__ __align__(16) ushort Bs[128][LDP];
  const int tid = threadIdx.x;
  const int lane = tid & 63, wave = tid >> 6;
  const int wr = wave >> 1, wc = wave & 1;
  const int row0 = blockIdx.y * 128, col0 = blockIdx.x * 128;
  const int r = tid >> 1, hf = tid & 1;

  f32x4 acc[4][4];
#pragma unroll
  for (int i = 0; i < 4; i++)
#pragma unroll
    for (int j = 0; j < 4; j++) acc[i][j] = {0.f, 0.f, 0.f, 0.f};

  const int lrow = lane & 15, lk = (lane >> 4) * 8;

  for (int k0 = 0; k0 < K; k0 += 32) {
    const float4* pa = (const float4*)(A + (size_t)(row0 + r) * K + k0 + hf * 16);
    const float4* pb = (const float4*)(Bt + (size_t)(col0 + r) * K + k0 + hf * 16);
    float4 a0 = pa[0], a1 = pa[1];
    float4 b0 = pb[0], b1 = pb[1];
    __syncthreads();
    *(float4*)&As[r][hf * 16] = a0;
    *(float4*)&As[r][hf * 16 + 8] = a1;
    *(float4*)&Bs[r][hf * 16] = b0;
    *(float4*)&Bs[r][hf * 16 + 8] = b1;
    __syncthreads();
    bfx8 af[4], bf[4];
#pragma unroll
    for (int mf = 0; mf < 4; mf++)
      af[mf] = *(const bfx8*)&As[wr * 64 + mf * 16 + lrow][lk];
#pragma unroll
    for (int nf = 0; nf < 4; nf++)
      bf[nf] = *(const bfx8*)&Bs[wc * 64 + nf * 16 + lrow][lk];
#pragma unroll
    for (int mf = 0; mf < 4; mf++)
#pragma unroll
      for (int nf = 0; nf < 4; nf++)
        acc[mf][nf] = __builtin_amdgcn_mfma_f32_16x16x32_bf16(af[mf], bf[nf], acc[mf][nf], 0, 0, 0);
  }
  const int crow = (lane >> 4) * 4, ccol = lane & 15;
#pragma unroll
  for (int mf = 0; mf < 4; mf++)
#pragma unroll
    for (int nf = 0; nf < 4; nf++)
#pragma unroll
      for (int rr = 0; rr < 4; rr++)
        C[(size_t)(row0 + wr * 64 + mf * 16 + crow + rr) * ldc + col0 + wc * 64 + nf * 16 + ccol] =
            acc[mf][nf][rr];
}

// ---------------- beta / gamma tiny projections (gamma = exp(g))
__global__ __launch_bounds__(256) void proj_bg(const float* __restrict__ hs,
                                               const float* __restrict__ Wb,
                                               const float* __restrict__ Wa,
                                               const float* __restrict__ A_log,
                                               const float* __restrict__ dt_bias,
                                               float* __restrict__ beta,
                                               float* __restrict__ g) {
  int row = blockIdx.x;
  int lane = threadIdx.x & 63;
  int wave = threadIdx.x >> 6;
  const float* x = hs + (size_t)row * HID;
  for (int out = wave; out < 12; out += 4) {
    float sum = 0.f;
    if (out < 8) {
      for (int k = lane; k < HID; k += 64) sum = fmaf(x[k], Wb[(size_t)k * 8 + out], sum);
    } else {
      int c = out - 8;
      for (int k = lane; k < HID; k += 64) sum = fmaf(x[k], Wa[(size_t)k * 4 + c], sum);
    }
    sum = wave_sum(sum);
    if (lane == 0) {
      if (out < 8) {
        beta[(size_t)row * 8 + out] = 2.f / (1.f + expf(-sum));
      } else {
        int h = out - 8;
        float xx = sum + dt_bias[h];
        float sp = (xx > 20.f) ? xx : log1pf(expf(xx));
        g[(size_t)row * 4 + h] = expf(-expf(A_log[h]) * sp);  // gamma
      }
    }
  }
}

// ---------------- conv+SiLU+l2norm for q -> pair-interleaved layout
// qbuf2[((b*512+tp)*4+h)*256 + (d>>1)*4 + (d&1) + (t&1)*2]
__global__ __launch_bounds__(128) void conv_q(const float* __restrict__ x, int ldx,
                                              const float* __restrict__ w,
                                              float* __restrict__ y, int T) {
  int rb = blockIdx.x;
  int h = rb % 4;
  int bt = rb / 4;
  int t = bt % T;
  int b = bt / T;
  int d = threadIdx.x;
  int c = h * 128 + d;
  const float* wc = w + (size_t)c * KSZ;
  float acc = 0.f;
#pragma unroll
  for (int i = 0; i < KSZ; i++) {
    int tt = t - (KSZ - 1) + i;
    if (tt >= 0) acc = fmaf(x[(size_t)(b * T + tt) * ldx + c], wc[i], acc);
  }
  float val = acc / (1.f + expf(-acc));
  float ss = wave_sum(val * val);
  __shared__ float sred[2];
  if ((threadIdx.x & 63) == 0) sred[threadIdx.x >> 6] = ss;
  __syncthreads();
  val *= rsqrtf(sred[0] + sred[1] + 1e-6f);
  y[((size_t)(b * 512 + (t >> 1)) * 4 + h) * 256 + (d >> 1) * 4 + (d & 1) + (t & 1) * 2] = val;
}

// ---------------- conv+SiLU+l2norm for k -> copy-interleaved layout
// kbuf2[((b*T+t)*4+h)*256 + (d>>1)*4 + (d&1) + i*2]
__global__ __launch_bounds__(128) void conv_k(const float* __restrict__ x, int ldx,
                                              const float* __restrict__ w,
                                              float* __restrict__ y, int T) {
  int rb = blockIdx.x;
  int gi = rb % 8;  // i*4 + h
  int bt = rb / 8;
  int t = bt % T;
  int b = bt / T;
  int i = gi >> 2, h = gi & 3;
  int d = threadIdx.x;
  int c = i * 512 + h * 128 + d;
  const float* wc = w + (size_t)c * KSZ;
  float acc = 0.f;
#pragma unroll
  for (int kk = 0; kk < KSZ; kk++) {
    int tt = t - (KSZ - 1) + kk;
    if (tt >= 0) acc = fmaf(x[(size_t)(b * T + tt) * ldx + c], wc[kk], acc);
  }
  float val = acc / (1.f + expf(-acc));
  float ss = wave_sum(val * val);
  __shared__ float sred[2];
  if ((threadIdx.x & 63) == 0) sred[threadIdx.x >> 6] = ss;
  __syncthreads();
  val *= rsqrtf(sred[0] + sred[1] + 1e-6f);
  y[((size_t)(b * T + t) * 4 + h) * 256 + (d >> 1) * 4 + (d & 1) + i * 2] = val;
}

// ---------------- conv+SiLU for v -> pair-major layout
// vbuf2[((b*512+tp)*4+h)*1024 + d*4 + (t&1)*2 + i]
__global__ __launch_bounds__(256) void conv_v(const float* __restrict__ x, int ldx,
                                              const float* __restrict__ w,
                                              float* __restrict__ y, int T) {
  int rb = blockIdx.x;
  int gi = rb % 8;  // i*4 + h
  int bt = rb / 8;
  int t = bt % T;
  int b = bt / T;
  int i = gi >> 2, h = gi & 3;
  int d = threadIdx.x;
  int c = i * 1024 + h * 256 + d;
  const float* wc = w + (size_t)c * KSZ;
  float acc = 0.f;
#pragma unroll
  for (int kk = 0; kk < KSZ; kk++) {
    int tt = t - (KSZ - 1) + kk;
    if (tt >= 0) acc = fmaf(x[(size_t)(b * T + tt) * ldx + c], wc[kk], acc);
  }
  float val = acc / (1.f + expf(-acc));
  y[((size_t)(b * 512 + (t >> 1)) * 4 + h) * 1024 + d * 4 + (t & 1) * 2 + i] = val;
}

// ---------------- 2-step coefficient records (24 floats per (b,tp,h))
// rec = {A0,A1,B10,gt | A2,B20,B21,gt1 | A3,B30,B31,B32 | E0,E1,G2,b0 | F0,F1,F2,F3 | b1,b2,b3,0}
__global__ __launch_bounds__(256) void cross_dots2(const float* __restrict__ kbuf2,
                                                   const float* __restrict__ qbuf2,
                                                   const float* __restrict__ beta,
                                                   const float* __restrict__ gam,
                                                   float* __restrict__ rec) {
  int idx = blockIdx.x * 4 + (threadIdx.x >> 6);  // (b*512+tp)*4 + h
  int lane = threadIdx.x & 63;
  int h = idx & 3, tp = (idx >> 2) & 511, b = idx >> 11;
  int t = 2 * tp;
  const float4 kA = *(const float4*)&kbuf2[((size_t)(b * 1024 + t) * 4 + h) * 256 + lane * 4];
  const float4 kB = *(const float4*)&kbuf2[((size_t)(b * 1024 + t + 1) * 4 + h) * 256 + lane * 4];
  const float4 qv = *(const float4*)&qbuf2[(size_t)idx * 256 + lane * 4];
  float d[12];
  d[0] = kA.z * kA.x + kA.w * kA.y;   // d10
  d[1] = kB.x * kA.x + kB.y * kA.y;   // d20
  d[2] = kB.x * kA.z + kB.y * kA.w;   // d21
  d[3] = kB.z * kA.x + kB.w * kA.y;   // d30
  d[4] = kB.z * kA.z + kB.w * kA.w;   // d31
  d[5] = kB.z * kB.x + kB.w * kB.y;   // d32
  d[6] = qv.x * kA.x + qv.y * kA.y;   // e00 = qt.k0
  d[7] = qv.x * kA.z + qv.y * kA.w;   // e01 = qt.k1
  d[8] = qv.z * kA.x + qv.w * kA.y;   // e10 = qt1.k0
  d[9] = qv.z * kA.z + qv.w * kA.w;   // e11 = qt1.k1
  d[10] = qv.z * kB.x + qv.w * kB.y;  // e12 = qt1.k2
  d[11] = qv.z * kB.z + qv.w * kB.w;  // e13 = qt1.k3
  dpp_reduce(d);
  int bt = b * 1024 + t;
  float b0 = beta[(size_t)(bt * 2 + 0) * 4 + h];
  float b1 = beta[(size_t)(bt * 2 + 1) * 4 + h];
  float b2 = beta[(size_t)(bt * 2 + 2) * 4 + h];
  float b3 = beta[(size_t)(bt * 2 + 3) * 4 + h];
  float gt = gam[(size_t)bt * 4 + h];
  float gt1 = gam[(size_t)(bt + 1) * 4 + h];
  if (lane == 0) {
    float G2 = gt * gt1;
    float4* rp = (float4*)&rec[(size_t)idx * 24];
    rp[0] = {b0 * gt, b1 * gt, b1 * d[0], gt};
    rp[1] = {b2 * G2, b2 * gt1 * d[1], b2 * gt1 * d[2], gt1};
    rp[2] = {b3 * G2, b3 * gt1 * d[3], b3 * gt1 * d[4], b3 * d[5]};
    rp[3] = {d[6], d[7], G2, b0};
    rp[4] = {gt1 * d[8], gt1 * d[9], d[10], d[11]};
    rp[5] = {b1, b2, b3, 0.f};
  }
}

// ---------------- 2-step batched gated-delta scan, one wave per (b,h,dv-column)
// Plain-C++ loads (R13-proven correct). This round: ROLLING-POINTER addressing —
// all loads at constant offsets off 5 incremented pointers (kA/kB share one biased
// pointer, offsets ±2048B within the 13-bit signed range). Kills the ~80-100
// VALU/pair of runtime-index 64-bit address math R13 paid, and shrinks live
// address state so the depth-2 FIFO stays register-resident.
__global__ __launch_bounds__(256, 2) void scan2(const float4* __restrict__ kb,
                                                const float4* __restrict__ qb,
                                                const float4* __restrict__ vb,
                                                const float4* __restrict__ rb,
                                                float* __restrict__ o) {
  const int lane = threadIdx.x & 63;
  const int wave = __builtin_amdgcn_readfirstlane(threadIdx.x >> 6);
  const int bh = blockIdx.x & 7;   // XCD-local
  const int cb = blockIdx.x >> 3;
  const int b = bh >> 2, h = bh & 3;
  const int col = cb * 4 + wave;

  // rolling pointers (float4 units); kp biased +128 so kA=-128, kB=+128 (±2048B offsets)
  const float4* kp = kb + ((size_t)(b * 1024) * 4 + h) * 64 + lane + 128;
  const float4* qp = qb + ((size_t)(b * 512) * 4 + h) * 64 + lane;
  const float4* vp = vb + ((size_t)(b * 512) * 4 + h) * 256 + col;
  const float4* rp = rb + ((size_t)(b * 512) * 4 + h) * 6;
  float* op = o + (size_t)(b * 1024) * NTOT + h * 256 + col;

  float sx = 0.f, sy = 0.f;

  float4 AkA, AkB, Aqv, Avv, AR0, AR1, AR2, AR3, AR4, AR5;
  float4 BkA, BkB, Bqv, Bvv, BR0, BR1, BR2, BR3, BR4, BR5;

#define LOADQ(P) { \
    P##kA = kp[-128]; \
    P##kB = kp[128]; \
    P##qv = qp[0]; \
    P##vv = vp[0]; \
    P##R0 = rp[0]; \
    P##R1 = rp[1]; \
    P##R2 = rp[2]; \
    P##R3 = rp[3]; \
    P##R4 = rp[4]; \
    P##R5 = rp[5]; \
    kp += 512; qp += 256; vp += 1024; rp += 24; }

#define STEPQ(P) { \
    float r[6]; \
    r[0] = P##kA.x * sx + P##kA.y * sy; \
    r[1] = P##kA.z * sx + P##kA.w * sy; \
    r[2] = P##kB.x * sx + P##kB.y * sy; \
    r[3] = P##kB.z * sx + P##kB.w * sy; \
    r[4] = P##qv.x * sx + P##qv.y * sy; \
    r[5] = P##qv.z * sx + P##qv.w * sy; \
    dpp_reduce(r); \
    float c0 = fmaf(-P##R0.x, r[0], P##R3.w * P##vv.x); \
    float c1 = fmaf(-P##R0.z, c0, fmaf(-P##R0.y, r[1], P##R5.x * P##vv.y)); \
    float c2 = fmaf(-P##R1.z, c1, fmaf(-P##R1.y, c0, fmaf(-P##R1.x, r[2], P##R5.y * P##vv.z))); \
    float c3 = fmaf(-P##R2.w, c2, fmaf(-P##R2.z, c1, fmaf(-P##R2.y, c0, \
               fmaf(-P##R2.x, r[3], P##R5.z * P##vv.w)))); \
    float ot = fmaf(P##R3.y, c1, fmaf(P##R3.x, c0, P##R0.w * r[4])); \
    float ot1 = fmaf(P##R4.w, c3, fmaf(P##R4.z, c2, fmaf(P##R4.y, c1, \
                fmaf(P##R4.x, c0, P##R3.z * r[5])))); \
    float g0 = P##R1.w * c0, g1 = P##R1.w * c1; \
    sx = fmaf(c3, P##kB.z, fmaf(c2, P##kB.x, fmaf(g1, P##kA.z, fmaf(g0, P##kA.x, P##R3.z * sx)))); \
    sy = fmaf(c3, P##kB.w, fmaf(c2, P##kB.y, fmaf(g1, P##kA.w, fmaf(g0, P##kA.y, P##R3.z * sy)))); \
    if (lane == 0) { op[0] = ot; op[NTOT] = ot1; } \
    op += 2 * NTOT; }

  LOADQ(A)
  LOADQ(B)
  for (int it = 0; it < 255; ++it) {
    STEPQ(A) LOADQ(A)
    STEPQ(B) LOADQ(B)
  }
  STEPQ(A)
  STEPQ(B)
#undef LOADQ
#undef STEPQ
}

// ---------------- RMSNorm(o) * w * SiLU(gate); writes dense bf16 [M][1024]
__global__ __launch_bounds__(256) void post_norm_gate(const float* __restrict__ o,
                                                      const float* __restrict__ gate,
                                                      const float* __restrict__ w,
                                                      ushort* __restrict__ obf) {
  int rb = blockIdx.x;
  int bt = rb >> 2, h = rb & 3;
  int tid = threadIdx.x;
  size_t ob = (size_t)bt * NTOT + h * 256 + tid;
  float ov = o[ob];
  float ss = wave_sum(ov * ov);
  __shared__ float sred[4];
  if ((tid & 63) == 0) sred[tid >> 6] = ss;
  __syncthreads();
  float tot = sred[0] + sred[1] + sred[2] + sred[3];
  float rms = rsqrtf(tot * (1.f / 256.f) + 1e-5f);
  float gt = gate[(size_t)bt * NTOT + h * 256 + tid];
  float val = ov * rms * w[tid] * (gt / (1.f + expf(-gt)));
  obf[(size_t)bt * HID + h * 256 + tid] = f2bf(val);
}

extern "C" void kernel_launch(void* const* d_in, const int* in_sizes, int n_in,
                              void* d_out, int out_size, void* d_ws, size_t ws_size,
                              hipStream_t stream) {
  const float* hs      = (const float*)d_in[0];
  const float* Wq      = (const float*)d_in[1];
  const float* Wk      = (const float*)d_in[2];
  const float* Wv      = (const float*)d_in[3];
  const float* Wb      = (const float*)d_in[4];
  const float* Wa      = (const float*)d_in[5];
  const float* Wg      = (const float*)d_in[6];
  const float* Wo      = (const float*)d_in[7];
  const float* A_log   = (const float*)d_in[8];
  const float* dt_bias = (const float*)d_in[9];
  const float* wq_conv = (const float*)d_in[10];
  const float* wk_conv = (const float*)d_in[11];
  const float* wv_conv = (const float*)d_in[12];
  const float* o_w     = (const float*)d_in[13];
  float* out = (float*)d_out;

  const int B = 2, T = 1024, M = B * T;

  float* ws    = (float*)d_ws;
  float* qkvg  = ws;                          // M*4608 fp32; cols 0..1023 get o; 3584+ gate
  float* kbuf  = qkvg + (size_t)M * NTOT;     // M*1024 (k interleaved)
  float* vbuf  = kbuf + (size_t)M * 1024;     // M*2048 (v pair-major)
  float* betab = vbuf + (size_t)M * 2048;     // M*8
  float* gb    = betab + (size_t)M * 8;       // M*4 (gamma)
  float* recb  = gb + (size_t)M * 4;          // 4096*24 floats
  float* qbuf  = out;                         // M*512 scratch (q pair-interleaved)

  // time-disjoint bf16 aliases in kbuf/vbuf regions:
  ushort* bqkvgT = (ushort*)kbuf;
  ushort* hsb    = (ushort*)(vbuf + (size_t)524288);  // vbuf + 2MB
  ushort* woT = (ushort*)kbuf;
  ushort* obf = (ushort*)vbuf;

  // casts + projections
  cast_hs<<<(M * HID / 4) / 256, 256, 0, stream>>>(hs, hsb);
  tr_pack<<<dim3(NTOT / 32, HID / 32), 256, 0, stream>>>(Wq, Wk, Wv, Wg, bqkvgT);
  gemm_bf16<<<dim3(NTOT / 128, M / 128), 256, 0, stream>>>(hsb, bqkvgT, qkvg, HID, NTOT);
  proj_bg<<<M, 256, 0, stream>>>(hs, Wb, Wa, A_log, dt_bias, betab, gb);
  // conv + SiLU (+ l2norm q,k) into scan-friendly layouts
  conv_q<<<M * 4, 128, 0, stream>>>(qkvg + 0, NTOT, wq_conv, qbuf, T);
  conv_k<<<M * 8, 128, 0, stream>>>(qkvg + 512, NTOT, wk_conv, kbuf, T);
  conv_v<<<M * 8, 256, 0, stream>>>(qkvg + 1536, NTOT, wv_conv, vbuf, T);
  // 2-step coefficient records
  cross_dots2<<<M * H / 8, 256, 0, stream>>>(kbuf, qbuf, betab, gb, recb);
  // batched scan -> o into qkvg cols 0..1023
  scan2<<<512, 256, 0, stream>>>((const float4*)kbuf, (const float4*)qbuf,
                                 (const float4*)vbuf, (const float4*)recb, qkvg);
  // epilogue + output projection
  post_norm_gate<<<M * H, 256, 0, stream>>>(qkvg, qkvg + 3584, o_w, obf);
  tr_one<<<dim3(HID / 32, HID / 32), 256, 0, stream>>>(Wo, woT, HID);
  gemm_bf16<<<dim3(HID / 128, M / 128), 256, 0, stream>>>(obf, woT, out, HID, HID);
}